// Round 18
// baseline (272.429 us; speedup 1.0000x reference)
//
#include <hip/hip_runtime.h>

#define FDIM 64

typedef unsigned short u16;
typedef unsigned int u32;
typedef float v2f __attribute__((ext_vector_type(2)));

__device__ __forceinline__ u16 f2bf(float x) {          // RNE f32->bf16
    unsigned int u = __float_as_uint(x);
    return (u16)((u + 0x7fff + ((u >> 16) & 1)) >> 16);
}
__device__ __forceinline__ float bf2f(u16 h) {
    return __uint_as_float(((unsigned int)h) << 16);
}
// pack 4 f32 -> 4 fp8 e4m3 (OCP on gfx950) in one u32
__device__ __forceinline__ u32 pk_fp8x4(float a, float b, float c, float d) {
    u32 p = __builtin_amdgcn_cvt_pk_fp8_f32(a, b, 0, false);
    p = __builtin_amdgcn_cvt_pk_fp8_f32(c, d, p, true);
    return p;
}

// ========= dense tile: t[64 rows] = act(ain + bias) @ W  (fp8 out) =========
// Known-good 52-VGPR structure: A staged to LDS f32, W in LDS.
// scale_cnt != nullptr: epilogue multiplies row R by rsqrt(cnt[R]+1)
// (rescale trick: t̂ = dinv_row * t -> aggregate needs no per-edge weights).

template <bool BF16IN>
__device__ __forceinline__ void mm_tile64(
    const void* __restrict__ ain, const float* __restrict__ bias, int do_relu,
    const int* __restrict__ scale_cnt,
    u32* __restrict__ t, int n, int blk,
    float (*__restrict__ As)[FDIM + 1], float* __restrict__ Ws)
{
    int tid = threadIdx.x;
    int r0 = blk * 64;

    #pragma unroll
    for (int i = 0; i < 4; ++i) {
        int idx = tid + 256 * i;
        int r = idx >> 4;
        int kq = idx & 15;
        float4 v = make_float4(0.f, 0.f, 0.f, 0.f);
        int R = r0 + r;
        if (R < n) {
            if (BF16IN) {
                ushort4 h = ((const ushort4*)ain)[(size_t)R * 16 + kq];
                v.x = bf2f(h.x); v.y = bf2f(h.y); v.z = bf2f(h.z); v.w = bf2f(h.w);
            } else {
                v = ((const float4*)ain)[(size_t)R * 16 + kq];
            }
            if (bias != nullptr) {
                float4 b = ((const float4*)bias)[kq];
                v.x += b.x; v.y += b.y; v.z += b.z; v.w += b.w;
            }
            if (do_relu) {
                v.x = fmaxf(v.x, 0.f); v.y = fmaxf(v.y, 0.f);
                v.z = fmaxf(v.z, 0.f); v.w = fmaxf(v.w, 0.f);
            }
        }
        As[r][kq * 4 + 0] = v.x;
        As[r][kq * 4 + 1] = v.y;
        As[r][kq * 4 + 2] = v.z;
        As[r][kq * 4 + 3] = v.w;
    }
    __syncthreads();

    int rq = tid >> 4;   // rows rq*4..+3
    int cq = tid & 15;   // cols cq*4..+3
    float acc[4][4];
    #pragma unroll
    for (int i = 0; i < 4; ++i)
        #pragma unroll
        for (int j = 0; j < 4; ++j) acc[i][j] = 0.f;

    const float4* Ws4 = (const float4*)Ws;
    #pragma unroll 4
    for (int k = 0; k < FDIM; ++k) {
        float4 w = Ws4[k * 16 + cq];
        float a[4];
        #pragma unroll
        for (int i = 0; i < 4; ++i) a[i] = As[rq * 4 + i][k];
        #pragma unroll
        for (int i = 0; i < 4; ++i) {
            acc[i][0] = fmaf(a[i], w.x, acc[i][0]);
            acc[i][1] = fmaf(a[i], w.y, acc[i][1]);
            acc[i][2] = fmaf(a[i], w.z, acc[i][2]);
            acc[i][3] = fmaf(a[i], w.w, acc[i][3]);
        }
    }

    #pragma unroll
    for (int i = 0; i < 4; ++i) {
        int R = r0 + rq * 4 + i;
        if (R < n) {
            float sc = 1.0f;
            if (scale_cnt != nullptr)
                sc = rsqrtf((float)scale_cnt[R] + 1.0f);
            t[(size_t)R * 16 + cq] =
                pk_fp8x4(acc[i][0] * sc, acc[i][1] * sc,
                         acc[i][2] * sc, acc[i][3] * sc);
        }
    }
}

// layers 2/3: A = bf16 agg; epilogue pre-scales by dinv_row
__global__ __launch_bounds__(256) void k_matmul_h(
    const u16* __restrict__ ain, const float* __restrict__ Wm,
    const float* __restrict__ bias, const int* __restrict__ cnt,
    u32* __restrict__ t, int n)
{
    __shared__ float As[64][FDIM + 1];
    __shared__ float Ws[FDIM * FDIM];
    int tid = threadIdx.x;
    #pragma unroll
    for (int i = 0; i < 4; ++i)
        ((float4*)Ws)[tid + 256 * i] = ((const float4*)Wm)[tid + 256 * i];
    mm_tile64<true>(ain, bias, 1, cnt, t, n, blockIdx.x, As, Ws);
}

// ===== combined dispatch: CSR-fill blocks (first) + matmul1 blocks =========
// Fill: unpartitioned grid-stride, 8 truly-independent atomics in flight.
// mm1 is UNSCALED (cnt not stable yet; layer-1 aggregate carries weights).

__global__ __launch_bounds__(256) void k_mm_fill(
    const float* __restrict__ x, const float* __restrict__ W1,
    u32* __restrict__ t,
    const int* __restrict__ src, const int* __restrict__ dst,
    int* __restrict__ cnt, int* __restrict__ csr,
    int n, int E, int cap, int fill_blocks)
{
    __shared__ float As[64][FDIM + 1];
    __shared__ float Ws[FDIM * FDIM];

    if ((int)blockIdx.x < fill_blocks) {
        int stride = fill_blocks * 256;
        int e = blockIdx.x * 256 + threadIdx.x;
        for (; e + 7 * stride < E; e += 8 * stride) {
            int d[8], s[8], p[8];
            #pragma unroll
            for (int u = 0; u < 8; ++u)
                d[u] = __builtin_nontemporal_load(&dst[e + u * stride]);
            #pragma unroll
            for (int u = 0; u < 8; ++u)
                s[u] = __builtin_nontemporal_load(&src[e + u * stride]);
            #pragma unroll
            for (int u = 0; u < 8; ++u) p[u] = atomicAdd(&cnt[d[u]], 1);
            #pragma unroll
            for (int u = 0; u < 8; ++u)
                if (p[u] < cap) csr[(size_t)d[u] * cap + p[u]] = s[u];
        }
        for (; e < E; e += stride) {
            int d = dst[e];
            int p = atomicAdd(&cnt[d], 1);
            if (p < cap) csr[(size_t)d * cap + p] = src[e];
        }
        return;
    }

    int blk = blockIdx.x - fill_blocks;
    int tid = threadIdx.x;
    #pragma unroll
    for (int i = 0; i < 4; ++i)
        ((float4*)Ws)[tid + 256 * i] = ((const float4*)W1)[tid + 256 * i];
    mm_tile64<false>(x, nullptr, 0, nullptr, t, n, blk, As, Ws);
}

// ======= gather-aggregate body for one node (16-lane group) ================
// SCALED: t rows already carry dinv_src -> pure gather-sum; invalid lanes
// point at the zeroed row ZR (=n) so no masking/weights needed.
// UNSCALED (layer 1): per-edge dj = rsqrt(cnt[src]+1) gathered+shuffled.

template <bool SCALED>
__device__ __forceinline__ float4 agg_node(
    int i, const int* __restrict__ cnt, const int* __restrict__ csr,
    const u32* __restrict__ t, int cap, int li, int nbase, int zr)
{
    int deg = cnt[i];
    float di = rsqrtf((float)deg + 1.0f);
    int m = deg < cap ? deg : cap;

    u32 sp = t[(size_t)i * 16 + li];
    v2f s0 = __builtin_amdgcn_cvt_pk_f32_fp8(sp, false);
    v2f s1 = __builtin_amdgcn_cvt_pk_f32_fp8(sp, true);
    // SCALED: t̂_i already = di*t_i (self term enters sum directly)
    // UNSCALED: self term needs di*t_i
    float sm = SCALED ? 1.0f : di;
    float4 A0 = make_float4(s0.x * sm, s0.y * sm, s1.x * sm, s1.y * sm);
    float4 A1 = make_float4(0.f, 0.f, 0.f, 0.f);
    float4 A2 = make_float4(0.f, 0.f, 0.f, 0.f);
    float4 A3 = make_float4(0.f, 0.f, 0.f, 0.f);

    const int* row = csr + (size_t)i * cap;

    for (int c0 = 0; c0 < m; c0 += 16) {
        int cm = m - c0; if (cm > 16) cm = 16;
        int sv = zr; float dvv = 0.f;
        if (li < cm) {
            sv = __builtin_nontemporal_load(&row[c0 + li]);
            if (!SCALED) dvv = rsqrtf((float)cnt[sv] + 1.0f);
        }
        if (SCALED) {
            int jv[16]; u32 v[16];
            #pragma unroll
            for (int u = 0; u < 16; ++u) jv[u] = __shfl(sv, nbase + u);
            #pragma unroll
            for (int u = 0; u < 16; ++u) v[u] = t[(size_t)jv[u] * 16 + li];
            #pragma unroll
            for (int u = 0; u < 16; ++u) {
                v2f x0 = __builtin_amdgcn_cvt_pk_f32_fp8(v[u], false);
                v2f x1 = __builtin_amdgcn_cvt_pk_f32_fp8(v[u], true);
                float4* Ap = (u & 3) == 0 ? &A0 : (u & 3) == 1 ? &A1 :
                             (u & 3) == 2 ? &A2 : &A3;
                Ap->x += x0.x; Ap->y += x0.y; Ap->z += x1.x; Ap->w += x1.y;
            }
        } else {
            int jv[16]; float dj[16]; u32 v[16];
            #pragma unroll
            for (int u = 0; u < 16; ++u) {
                jv[u] = __shfl(sv, nbase + u);
                dj[u] = __shfl(dvv, nbase + u);
            }
            #pragma unroll
            for (int u = 0; u < 16; ++u) v[u] = t[(size_t)jv[u] * 16 + li];
            #pragma unroll
            for (int u = 0; u < 16; ++u) {
                v2f x0 = __builtin_amdgcn_cvt_pk_f32_fp8(v[u], false);
                v2f x1 = __builtin_amdgcn_cvt_pk_f32_fp8(v[u], true);
                float4* Ap = (u & 3) == 0 ? &A0 : (u & 3) == 1 ? &A1 :
                             (u & 3) == 2 ? &A2 : &A3;
                Ap->x = fmaf(x0.x, dj[u], Ap->x);
                Ap->y = fmaf(x0.y, dj[u], Ap->y);
                Ap->z = fmaf(x1.x, dj[u], Ap->z);
                Ap->w = fmaf(x1.y, dj[u], Ap->w);
            }
        }
    }

    float4 O;
    O.x = ((A0.x + A1.x) + (A2.x + A3.x)) * di;
    O.y = ((A0.y + A1.y) + (A2.y + A3.y)) * di;
    O.z = ((A0.z + A1.z) + (A2.z + A3.z)) * di;
    O.w = ((A0.w + A1.w) + (A2.w + A3.w)) * di;
    return O;
}

// == aggregate: bf16 out, 4 nodes/wave, 16-lane groups ==

template <bool SCALED>
__global__ __launch_bounds__(256) void k_aggregate(
    const int* __restrict__ cnt, const int* __restrict__ csr,
    const u32* __restrict__ t, uint2* __restrict__ aggh, int n, int cap)
{
    int tid = threadIdx.x;
    long long gw = ((long long)blockIdx.x * 256 + tid) >> 6;
    int lane = tid & 63;
    int sub = lane >> 4;
    int li  = lane & 15;
    long long il = gw * 4 + sub;
    if (il >= n) return;
    int i = (int)il;

    float4 O = agg_node<SCALED>(i, cnt, csr, t, cap, li, sub << 4, n);
    uint2 pk;
    pk.x = ((u32)f2bf(O.x)) | (((u32)f2bf(O.y)) << 16);
    pk.y = ((u32)f2bf(O.z)) | (((u32)f2bf(O.w)) << 16);
    aggh[(size_t)i * 16 + li] = pk;
}

// == layer-3 aggregate (SCALED t) fused with pool: block = (graph, part) ==

__global__ __launch_bounds__(256) void k_agg_pool(
    const int* __restrict__ cnt, const int* __restrict__ csr,
    const u32* __restrict__ t, const int* __restrict__ batch,
    float* __restrict__ partial, int n, int cap, int npart)
{
    int g = blockIdx.x / npart;
    int part = blockIdx.x - g * npart;
    int tid = threadIdx.x;

    int lo = 0, hi = n;
    while (lo < hi) { int mid = (lo + hi) >> 1; if (batch[mid] < g) lo = mid + 1; else hi = mid; }
    int start = lo;
    hi = n;
    while (lo < hi) { int mid = (lo + hi) >> 1; if (batch[mid] <= g) lo = mid + 1; else hi = mid; }
    int end = lo;

    int group = tid >> 4;     // 0..15
    int li = tid & 15;
    int lane = tid & 63;
    int nbase = (lane >> 4) << 4;

    float4 acc = make_float4(0.f, 0.f, 0.f, 0.f);
    for (int i = start + part * 16 + group; i < end; i += npart * 16) {
        float4 O = agg_node<true>(i, cnt, csr, t, cap, li, nbase, n);
        acc.x += O.x; acc.y += O.y; acc.z += O.z; acc.w += O.w;
    }

    __shared__ float4 red[16][16];
    red[group][li] = acc;
    __syncthreads();
    if (tid < 16) {
        float4 s = make_float4(0.f, 0.f, 0.f, 0.f);
        #pragma unroll
        for (int q = 0; q < 16; ++q) {
            s.x += red[q][tid].x; s.y += red[q][tid].y;
            s.z += red[q][tid].z; s.w += red[q][tid].w;
        }
        ((float4*)partial)[((size_t)g * npart + part) * 16 + tid] = s;
    }
}

__global__ __launch_bounds__(64) void k_pool2(
    const float* __restrict__ partial, const int* __restrict__ batch,
    const float* __restrict__ b3, const float* __restrict__ Wlin,
    const float* __restrict__ blin, float* __restrict__ out,
    int n, int fout, int npart)
{
    int g = blockIdx.x;
    int tid = threadIdx.x;

    int lo = 0, hi = n;
    while (lo < hi) { int mid = (lo + hi) >> 1; if (batch[mid] < g) lo = mid + 1; else hi = mid; }
    int start = lo;
    hi = n;
    while (lo < hi) { int mid = (lo + hi) >> 1; if (batch[mid] <= g) lo = mid + 1; else hi = mid; }
    int cnt = lo - start;

    __shared__ float pooled[64];
    float v = 0.f;
    for (int p = 0; p < npart; ++p)
        v += partial[((size_t)g * npart + p) * 64 + tid];
    pooled[tid] = (cnt > 0) ? (v / (float)cnt + b3[tid]) : 0.f;
    __syncthreads();
    if (tid < fout) {
        float o = blin[tid];
        for (int k = 0; k < 64; ++k) o += pooled[k] * Wlin[k * fout + tid];
        out[(size_t)g * fout + tid] = o;
    }
}

// ================= launcher =================

extern "C" void kernel_launch(void* const* d_in, const int* in_sizes, int n_in,
                              void* d_out, int out_size, void* d_ws, size_t ws_size,
                              hipStream_t stream) {
    const float* x     = (const float*)d_in[0];
    const int*   ei    = (const int*)d_in[1];
    const int*   batch = (const int*)d_in[2];
    const float* W1 = (const float*)d_in[3];
    const float* b1 = (const float*)d_in[4];
    const float* W2 = (const float*)d_in[5];
    const float* b2 = (const float*)d_in[6];
    const float* W3 = (const float*)d_in[7];
    const float* b3 = (const float*)d_in[8];
    const float* Wl = (const float*)d_in[9];
    const float* bl = (const float*)d_in[10];

    int n = in_sizes[0] / 64;
    int E = in_sizes[1] / 2;
    int fout = in_sizes[10];
    int ngraphs = out_size / fout;

    const int* srcp = ei;
    const int* dstp = ei + E;

    const int npart = 16;

    // ws layout: agg bf16 | t fp8 (n+1 rows: row n = zero row) | partial | cnt | csr
    float* ws   = (float*)d_ws;
    u32*   agg  = (u32*)ws;                          // n*32 u32 (bf16 pairs)
    u32*   t    = agg + (size_t)n * 32;              // (n+1)*16 u32 (fp8 rows)
    float* partial = (float*)(t + (size_t)(n + 1) * 16); // 64*16*64
    int* cnt    = (int*)(partial + 64 * npart * 64); // n
    int* csr    = cnt + n;                           // n*cap

    size_t fixed = (size_t)n * 32 * 4 + (size_t)(n + 1) * 16 * 4 +
                   64 * npart * 64 * 4 + (size_t)n * 4;
    int cap = 64;
    while (cap > 32 && fixed + (size_t)n * cap * 4 > ws_size) cap -= 8;

    int nb_ag = (int)((((long long)(n + 3) / 4) * 64 + 255) / 256);
    int mm_blocks = (n + 63) / 64;
    int fill_blocks = 256;

    hipMemsetAsync(cnt, 0, (size_t)n * sizeof(int), stream);
    hipMemsetAsync(t + (size_t)n * 16, 0, 64, stream);   // zero row (gather sink)
    // CSR build (unpartitioned, 8-deep) + t1 = x @ W1 (fp8, unscaled)
    k_mm_fill<<<fill_blocks + mm_blocks, 256, 0, stream>>>(
        x, W1, t, srcp, dstp, cnt, csr, n, E, cap, fill_blocks);

    // layer 1 aggregate (weighted) -> bf16 agg
    k_aggregate<false><<<nb_ag, 256, 0, stream>>>(cnt, csr, t, (uint2*)agg, n, cap);
    // layer 2: matmul pre-scales by dinv_row -> SCALED aggregate (pure sum)
    k_matmul_h<<<mm_blocks, 256, 0, stream>>>((const u16*)agg, W2, b1, cnt, t, n);
    k_aggregate<true><<<nb_ag, 256, 0, stream>>>(cnt, csr, t, (uint2*)agg, n, cap);
    // layer 3
    k_matmul_h<<<mm_blocks, 256, 0, stream>>>((const u16*)agg, W3, b2, cnt, t, n);
    k_agg_pool<<<ngraphs * npart, 256, 0, stream>>>(cnt, csr, t, batch,
                                                    partial, n, cap, npart);
    k_pool2<<<ngraphs, 64, 0, stream>>>(partial, batch, b3, Wl, bl,
                                        (float*)d_out, n, fout, npart);
}